// Round 1
// 190.651 us; speedup vs baseline: 1.0602x; 1.0602x over previous
//
#include <hip/hip_runtime.h>
#include <hip/hip_bf16.h>
#include <math.h>

// Problem constants (PoseMixtureVAE)
#define N_BATCH 4096
#define FRAME   267
#define LATENT  32
#define HIDDEN  256
#define GATE_H  64
#define EXPERTS 6
// Kpads: [x|c]=534->544 (17 ksteps), [x|h]=523->544 (17), [z|c]=299->320 (10),
//        [z|h]=288 (9), gate hidden 64 (2)

typedef __hip_bfloat16 bf16;
typedef __bf16  bf16x8 __attribute__((ext_vector_type(8)));
typedef float   f32x4  __attribute__((ext_vector_type(4)));

__device__ __forceinline__ float eluf(float v) { return (v > 0.f) ? v : (expf(v) - 1.f); }

struct WEnt { const float* src; bf16* dst; int K, M, Mtot, mOff, Ksteps, Mtiles, cum; };
struct WTab { WEnt e[10]; int total; };

// ---------------------------------------------------------------------------
// prep: input conversion (blocks 0..511, 8 rows each) + weight repack
// (blocks 512.., one 32x32 tile unit each) + biasCat.
// ---------------------------------------------------------------------------
__global__ __launch_bounds__(256) void prep_kernel(
    const float* __restrict__ x, const float* __restrict__ c,
    const float* __restrict__ bmu, const float* __restrict__ blv,
    bf16* __restrict__ Axc, bf16* __restrict__ Axh1,
    bf16* __restrict__ Axh2, bf16* __restrict__ Azc,
    float* __restrict__ biasCat, WTab tab)
{
    const int tid = threadIdx.x, bid = blockIdx.x;
    if (bid < 512) {
        if (bid == 0 && tid < 64)
            biasCat[tid] = (tid < 32) ? bmu[tid] : blv[tid - 32];
        #pragma unroll 1
        for (int i = 0; i < 8; ++i) {
            const int r = bid * 8 + i;
            for (int col = tid; col < 544; col += 256) {
                const size_t o = (size_t)r * 544 + col;
                float vx = 0.f;
                if (col < FRAME)          vx = x[(size_t)r * FRAME + col];
                else if (col < 2 * FRAME) vx = c[(size_t)r * FRAME + col - FRAME];
                Axc[o] = __float2bfloat16(vx);
                if (col < FRAME) {
                    const bf16 v = __float2bfloat16(x[(size_t)r * FRAME + col]);
                    Axh1[o] = v; Axh2[o] = v;
                } else if (col >= FRAME + HIDDEN) {
                    const bf16 zv = __float2bfloat16(0.f);
                    Axh1[o] = zv; Axh2[o] = zv;
                }
                if (col >= 32 && col < 320) {
                    const float vc = (col < 32 + FRAME) ? c[(size_t)r * FRAME + col - 32] : 0.f;
                    Azc[(size_t)r * 320 + col] = __float2bfloat16(vc);
                }
            }
        }
        return;
    }
    // weight repack unit
    __shared__ float tbuf[32][33];
    const int u = bid - 512;
    int i = 0;
    while (i < 9 && u >= tab.e[i + 1].cum) ++i;
    const WEnt en = tab.e[i];
    const int t = u - en.cum;
    const int perE = en.Ksteps * en.Mtiles;
    const int e = t / perE;
    const int rr = t - e * perE;
    const int mt = rr / en.Ksteps;
    const int ks = rr - mt * en.Ksteps;
    const int tx = tid & 31, ty = tid >> 5;
    const float* src = en.src + (size_t)e * en.K * en.M;
    #pragma unroll
    for (int i0 = 0; i0 < 32; i0 += 8) {
        const int k = ks * 32 + i0 + ty, m = mt * 32 + tx;
        tbuf[i0 + ty][tx] = (k < en.K && m < en.M) ? src[(size_t)k * en.M + m] : 0.f;
    }
    __syncthreads();
    bf16* dst = en.dst + ((size_t)(e * en.Ksteps + ks) * en.Mtot + en.mOff + mt * 32) * 32;
    #pragma unroll
    for (int i0 = 0; i0 < 32; i0 += 8)
        dst[(size_t)(i0 + ty) * 32 + tx] = __float2bfloat16(tbuf[tx][i0 + ty]);
}

// ---------------------------------------------------------------------------
// 16-row MFMA GEMM (TLP-first) — used for the E=1 encoder layers.
// Block = 16 rows x 64 cols, 4 waves, each wave exactly ONE 16-col tile.
// ---------------------------------------------------------------------------
template<int KSTEPS, int E>
__global__ __launch_bounds__(256, 4) void gemm16(
    const bf16* __restrict__ A, const bf16* __restrict__ Wt,
    const float* __restrict__ bias, const float* __restrict__ coeff,
    int M, int Mtot,
    float* __restrict__ Cf, int ldc, bf16* __restrict__ Cb, int ldcb, int act)
{
    constexpr int Kpad = KSTEPS * 32;
    constexpr int strideA = Kpad + 8;
    __shared__ bf16  sA[16 * strideA];
    __shared__ float sCo[E * 16];

    const int tid = threadIdx.x;
    const int w = tid >> 6, lane = tid & 63, ml = lane & 15, quad = lane >> 4;
    const int row0 = blockIdx.y * 16;
    const int col  = blockIdx.x * 64 + 16 * w + ml;

    if (tid < 16 * E) {
        const int e = tid >> 4, r = tid & 15;
        sCo[tid] = coeff ? coeff[(size_t)(row0 + r) * EXPERTS + e] : 1.f;
    }
    {   // stage A: 16 rows x Kpad, 16 threads/row x 16B chunks
        const int r = tid >> 4, kt = (tid & 15) * 8;
        for (int kk = kt; kk < Kpad; kk += 128)
            *(float4*)(sA + r * strideA + kk) =
                *(const float4*)(A + (size_t)(row0 + r) * Kpad + kk);
    }
    __syncthreads();

    f32x4 acc = (f32x4){0.f, 0.f, 0.f, 0.f};
    for (int e = 0; e < E; ++e) {
        f32x4 p = (f32x4){0.f, 0.f, 0.f, 0.f};
        const bf16* wp = Wt + ((size_t)e * KSTEPS * Mtot + col) * 32 + quad * 8;
        #pragma unroll
        for (int ks = 0; ks < KSTEPS; ++ks) {
            const bf16x8 b  = *(const bf16x8*)(wp + (size_t)ks * Mtot * 32);
            const bf16x8 av = *(const bf16x8*)(sA + ml * strideA + ks * 32 + quad * 8);
            p = __builtin_amdgcn_mfma_f32_16x16x32_bf16(av, b, p, 0, 0, 0);
        }
        const float bv = (col < M) ? bias[(size_t)e * M + col] : 0.f;
        #pragma unroll
        for (int rg = 0; rg < 4; ++rg)
            acc[rg] += sCo[e * 16 + quad * 4 + rg] * (p[rg] + bv);
    }

    if (col < M) {
        #pragma unroll
        for (int rg = 0; rg < 4; ++rg) {
            const int gr = row0 + quad * 4 + rg;
            float v = acc[rg];
            if (act) v = eluf(v);
            if (Cf) Cf[(size_t)gr * ldc + col] = v;
            if (Cb) Cb[(size_t)gr * ldcb + col] = __float2bfloat16(v);
        }
    }
}

// ---------------------------------------------------------------------------
// 32-row MFMA GEMM (row-RF=2) — used for the E=6 MoE layers.
// Block = 32 rows x 64 cols, 4 waves; each wave ONE 16-col tile x TWO 16-row
// groups sharing every B fragment -> 2 MFMA per 1KB B-load, half the total
// B stream vs the 16-row version. Grid (Mtot/64, 128) = 512+ blocks = 2/CU.
// __launch_bounds__(256,2): <=256 VGPR is enough for 2 blocks/CU residency.
// ---------------------------------------------------------------------------
template<int KSTEPS, int E>
__global__ __launch_bounds__(256, 2) void gemm32(
    const bf16* __restrict__ A, const bf16* __restrict__ Wt,
    const float* __restrict__ bias, const float* __restrict__ coeff,
    int M, int Mtot,
    float* __restrict__ Cf, int ldc, bf16* __restrict__ Cb, int ldcb, int act)
{
    constexpr int Kpad = KSTEPS * 32;
    constexpr int strideA = Kpad + 8;
    __shared__ bf16  sA[32 * strideA];
    __shared__ float sCo[E * 32];

    const int tid = threadIdx.x;
    const int w = tid >> 6, lane = tid & 63, ml = lane & 15, quad = lane >> 4;
    const int row0 = blockIdx.y * 32;
    const int col  = blockIdx.x * 64 + 16 * w + ml;

    if (tid < 32 * E) {
        const int e = tid >> 5, r = tid & 31;
        sCo[tid] = coeff ? coeff[(size_t)(row0 + r) * EXPERTS + e] : 1.f;
    }
    {   // stage A: 32 rows x Kpad, 8 threads/row x 16B chunks
        const int r = tid >> 3, kt = (tid & 7) * 8;
        for (int kk = kt; kk < Kpad; kk += 64)
            *(float4*)(sA + r * strideA + kk) =
                *(const float4*)(A + (size_t)(row0 + r) * Kpad + kk);
    }
    __syncthreads();

    f32x4 acc0 = (f32x4){0.f, 0.f, 0.f, 0.f};
    f32x4 acc1 = (f32x4){0.f, 0.f, 0.f, 0.f};
    for (int e = 0; e < E; ++e) {
        f32x4 p0 = (f32x4){0.f, 0.f, 0.f, 0.f};
        f32x4 p1 = (f32x4){0.f, 0.f, 0.f, 0.f};
        const bf16* wp = Wt + ((size_t)e * KSTEPS * Mtot + col) * 32 + quad * 8;
        #pragma unroll
        for (int ks = 0; ks < KSTEPS; ++ks) {
            const bf16x8 b  = *(const bf16x8*)(wp + (size_t)ks * Mtot * 32);
            const bf16x8 a0 = *(const bf16x8*)(sA + ml * strideA + ks * 32 + quad * 8);
            const bf16x8 a1 = *(const bf16x8*)(sA + (16 + ml) * strideA + ks * 32 + quad * 8);
            p0 = __builtin_amdgcn_mfma_f32_16x16x32_bf16(a0, b, p0, 0, 0, 0);
            p1 = __builtin_amdgcn_mfma_f32_16x16x32_bf16(a1, b, p1, 0, 0, 0);
        }
        const float bv = (col < M) ? bias[(size_t)e * M + col] : 0.f;
        #pragma unroll
        for (int rg = 0; rg < 4; ++rg) {
            acc0[rg] += sCo[e * 32 + quad * 4 + rg]      * (p0[rg] + bv);
            acc1[rg] += sCo[e * 32 + 16 + quad * 4 + rg] * (p1[rg] + bv);
        }
    }

    if (col < M) {
        #pragma unroll
        for (int rg = 0; rg < 4; ++rg) {
            const int gr0 = row0 + quad * 4 + rg;
            const int gr1 = gr0 + 16;
            float v0 = acc0[rg], v1 = acc1[rg];
            if (act) { v0 = eluf(v0); v1 = eluf(v1); }
            if (Cf) {
                Cf[(size_t)gr0 * ldc + col] = v0;
                Cf[(size_t)gr1 * ldc + col] = v1;
            }
            if (Cb) {
                Cb[(size_t)gr0 * ldcb + col] = __float2bfloat16(v0);
                Cb[(size_t)gr1 * ldcb + col] = __float2bfloat16(v1);
            }
        }
    }
}

// ---------------------------------------------------------------------------
// mid: mu|lv GEMM (M=64) + z + gate chain (g1,g2,logits) + softmax.
// 16-row blocks -> grid 256 (1/CU). All deps block-local.
// ---------------------------------------------------------------------------
__global__ __launch_bounds__(256) void mid_kernel(
    const bf16* __restrict__ Axh2, const bf16* __restrict__ Wt_ml,
    const float* __restrict__ biasCat, const float* __restrict__ eps,
    float* __restrict__ out_mu, float* __restrict__ out_lv,
    bf16* __restrict__ Azc, bf16* __restrict__ Azd1, bf16* __restrict__ Azd2,
    const bf16* __restrict__ Wg0, const bf16* __restrict__ Wg1,
    const bf16* __restrict__ Wg2,
    const float* __restrict__ gb0, const float* __restrict__ gb1,
    const float* __restrict__ gb2, float* __restrict__ co)
{
    __shared__ bf16 sA[16 * 552];
    __shared__ char r1[8192];
    const int tid = threadIdx.x;
    const int w = tid >> 6, lane = tid & 63, ml = lane & 15, quad = lane >> 4;
    const int row0 = blockIdx.x * 16;

    float* sML = (float*)r1;                       // 16x64 f32 = 4KB
    {   // stage Axh2 rows (Kpad 544, stride 552)
        const int r = tid >> 4, kt = (tid & 15) * 8;
        for (int kk = kt; kk < 544; kk += 128)
            *(float4*)(sA + r * 552 + kk) =
                *(const float4*)(Axh2 + (size_t)(row0 + r) * 544 + kk);
    }
    __syncthreads();
    {   // mu|lv: M=64, wave w -> cols 16w..16w+15 (16 rows, RF=1)
        const int col = 16 * w + ml;
        f32x4 p = (f32x4){0.f, 0.f, 0.f, 0.f};
        const bf16* wp = Wt_ml + (size_t)col * 32 + quad * 8;
        #pragma unroll
        for (int ks = 0; ks < 17; ++ks) {
            const bf16x8 b  = *(const bf16x8*)(wp + (size_t)ks * 64 * 32);
            const bf16x8 av = *(const bf16x8*)(sA + ml * 552 + ks * 32 + quad * 8);
            p = __builtin_amdgcn_mfma_f32_16x16x32_bf16(av, b, p, 0, 0, 0);
        }
        const float bv = biasCat[col];
        #pragma unroll
        for (int rg = 0; rg < 4; ++rg)
            sML[(quad * 4 + rg) * 64 + col] = p[rg] + bv;
    }
    __syncthreads();
    for (int i = tid; i < 16 * LATENT; i += 256) {
        const int r = i >> 5, l = i & 31;
        const float m  = sML[r * 64 + l];
        const float lv = sML[r * 64 + 32 + l];
        const int gi = (row0 + r) * LATENT + l;
        out_mu[gi] = m; out_lv[gi] = lv;
        const bf16 zb = __float2bfloat16(m + eps[gi] * expf(0.5f * lv));
        Azc [(size_t)(row0 + r) * 320 + l] = zb;
        Azd1[(size_t)(row0 + r) * 288 + l] = zb;
        Azd2[(size_t)(row0 + r) * 288 + l] = zb;
    }
    __syncthreads();
    {   // re-stage gate A = Azc rows [z|c] (Kpad 320, stride 328)
        const int r = tid >> 4, kt = (tid & 15) * 8;
        for (int kk = kt; kk < 320; kk += 128)
            *(float4*)(sA + r * 328 + kk) =
                *(const float4*)(Azc + (size_t)(row0 + r) * 320 + kk);
    }
    bf16*  sG1 = (bf16*)r1;                        // 16x72 bf16 = 2304B
    bf16*  sG2 = (bf16*)(r1 + 2304);
    float* sLg = (float*)(r1 + 4608);              // 16x16 f32 = 1024B
    __syncthreads();
    {   // g1: K=320(10), M=64
        const int col = 16 * w + ml;
        f32x4 p = (f32x4){0.f, 0.f, 0.f, 0.f};
        const bf16* wp = Wg0 + (size_t)col * 32 + quad * 8;
        #pragma unroll
        for (int ks = 0; ks < 10; ++ks) {
            const bf16x8 b  = *(const bf16x8*)(wp + (size_t)ks * 64 * 32);
            const bf16x8 av = *(const bf16x8*)(sA + ml * 328 + ks * 32 + quad * 8);
            p = __builtin_amdgcn_mfma_f32_16x16x32_bf16(av, b, p, 0, 0, 0);
        }
        const float bv = gb0[col];
        #pragma unroll
        for (int rg = 0; rg < 4; ++rg)
            sG1[(quad * 4 + rg) * 72 + col] = __float2bfloat16(eluf(p[rg] + bv));
    }
    __syncthreads();
    {   // g2: K=64(2), M=64
        const int col = 16 * w + ml;
        f32x4 p = (f32x4){0.f, 0.f, 0.f, 0.f};
        const bf16* wp = Wg1 + (size_t)col * 32 + quad * 8;
        #pragma unroll
        for (int ks = 0; ks < 2; ++ks) {
            const bf16x8 b  = *(const bf16x8*)(wp + (size_t)ks * 64 * 32);
            const bf16x8 av = *(const bf16x8*)(sG1 + ml * 72 + ks * 32 + quad * 8);
            p = __builtin_amdgcn_mfma_f32_16x16x32_bf16(av, b, p, 0, 0, 0);
        }
        const float bv = gb1[col];
        #pragma unroll
        for (int rg = 0; rg < 4; ++rg)
            sG2[(quad * 4 + rg) * 72 + col] = __float2bfloat16(eluf(p[rg] + bv));
    }
    __syncthreads();
    if (w == 0) {   // logits: K=64(2), M=6 (Mtot 32)
        f32x4 p = (f32x4){0.f, 0.f, 0.f, 0.f};
        const bf16* wp = Wg2 + (size_t)ml * 32 + quad * 8;
        #pragma unroll
        for (int ks = 0; ks < 2; ++ks) {
            const bf16x8 b  = *(const bf16x8*)(wp + (size_t)ks * 32 * 32);
            const bf16x8 av = *(const bf16x8*)(sG2 + ml * 72 + ks * 32 + quad * 8);
            p = __builtin_amdgcn_mfma_f32_16x16x32_bf16(av, b, p, 0, 0, 0);
        }
        const float bv = (ml < EXPERTS) ? gb2[ml] : 0.f;
        #pragma unroll
        for (int rg = 0; rg < 4; ++rg)
            sLg[(quad * 4 + rg) * 16 + ml] = p[rg] + bv;
    }
    __syncthreads();
    if (tid < 16) {
        float v[EXPERTS];
        float m = -1e30f;
        #pragma unroll
        for (int i = 0; i < EXPERTS; ++i) { v[i] = sLg[tid * 16 + i]; m = fmaxf(m, v[i]); }
        float s = 0.f;
        #pragma unroll
        for (int i = 0; i < EXPERTS; ++i) { v[i] = expf(v[i] - m); s += v[i]; }
        const float inv = 1.f / s;
        #pragma unroll
        for (int i = 0; i < EXPERTS; ++i)
            co[(size_t)(row0 + tid) * EXPERTS + i] = v[i] * inv;
    }
}

// ---------------------------------------------------------------------------
extern "C" void kernel_launch(void* const* d_in, const int* in_sizes, int n_in,
                              void* d_out, int out_size, void* d_ws, size_t ws_size,
                              hipStream_t stream) {
    const float* x       = (const float*)d_in[0];
    const float* c       = (const float*)d_in[1];
    const float* eps     = (const float*)d_in[2];
    const float* enc_w1  = (const float*)d_in[3];
    const float* enc_b1  = (const float*)d_in[4];
    const float* enc_w2  = (const float*)d_in[5];
    const float* enc_b2  = (const float*)d_in[6];
    const float* enc_wmu = (const float*)d_in[7];
    const float* enc_bmu = (const float*)d_in[8];
    const float* enc_wlv = (const float*)d_in[9];
    const float* enc_blv = (const float*)d_in[10];
    const float* g_w0    = (const float*)d_in[11];
    const float* g_b0    = (const float*)d_in[12];
    const float* g_w1    = (const float*)d_in[13];
    const float* g_b1    = (const float*)d_in[14];
    const float* g_w2    = (const float*)d_in[15];
    const float* g_b2    = (const float*)d_in[16];
    const float* w0      = (const float*)d_in[17];
    const float* b0      = (const float*)d_in[18];
    const float* w1      = (const float*)d_in[19];
    const float* b1      = (const float*)d_in[20];
    const float* w2      = (const float*)d_in[21];
    const float* b2      = (const float*)d_in[22];

    // output (f32): [layer (4096x267) | mu (4096x32) | logvar (4096x32)]
    float* out_layer = (float*)d_out;
    float* out_mu    = out_layer + (size_t)N_BATCH * FRAME;
    float* out_lv    = out_mu    + (size_t)N_BATCH * LATENT;

    // ---- workspace layout (16B-aligned) ----
    char* p = (char*)d_ws;
    float* co      = (float*)p;  p += (size_t)N_BATCH * EXPERTS * 4;
    float* biasCat = (float*)p;  p += 64 * 4;
    bf16* Axc   = (bf16*)p;      p += (size_t)N_BATCH * 544 * 2;
    bf16* Axh1  = (bf16*)p;      p += (size_t)N_BATCH * 544 * 2;
    bf16* Axh2  = (bf16*)p;      p += (size_t)N_BATCH * 544 * 2;
    bf16* Azc   = (bf16*)p;      p += (size_t)N_BATCH * 320 * 2;
    bf16* Azd1  = (bf16*)p;      p += (size_t)N_BATCH * 288 * 2;
    bf16* Azd2  = (bf16*)p;      p += (size_t)N_BATCH * 288 * 2;
    bf16* Wt_e1 = (bf16*)p;      p += (size_t)17 * 256 * 32 * 2;
    bf16* Wt_e2 = (bf16*)p;      p += (size_t)17 * 256 * 32 * 2;
    bf16* Wt_ml = (bf16*)p;      p += (size_t)17 * 64 * 32 * 2;
    bf16* Wt_g0 = (bf16*)p;      p += (size_t)10 * 64 * 32 * 2;
    bf16* Wt_g1 = (bf16*)p;      p += (size_t)2 * 64 * 32 * 2;
    bf16* Wt_g2 = (bf16*)p;      p += (size_t)2 * 32 * 32 * 2;
    bf16* Wt_w0 = (bf16*)p;      p += (size_t)EXPERTS * 10 * 256 * 32 * 2;
    bf16* Wt_w1 = (bf16*)p;      p += (size_t)EXPERTS * 9 * 256 * 32 * 2;
    bf16* Wt_w2 = (bf16*)p;      p += (size_t)EXPERTS * 9 * 320 * 32 * 2;

    WTab tab;
    int cum = 0, n = 0;
    auto add = [&](const float* src, bf16* dst, int K, int M, int Mtot, int mOff, int E) {
        int Ksteps;
        if (K == 534 || K == 523) Ksteps = 17;
        else if (K == 299) Ksteps = 10;
        else if (K == 288) Ksteps = 9;
        else Ksteps = 2;   // K=64
        const int Mtiles = (M + 31) / 32;
        tab.e[n] = {src, dst, K, M, Mtot, mOff, Ksteps, Mtiles, cum};
        cum += E * Ksteps * Mtiles;
        ++n;
    };
    add(enc_w1,  Wt_e1, 534, 256, 256, 0, 1);
    add(enc_w2,  Wt_e2, 523, 256, 256, 0, 1);
    add(enc_wmu, Wt_ml, 523, 32, 64, 0, 1);
    add(enc_wlv, Wt_ml, 523, 32, 64, 32, 1);
    add(g_w0,    Wt_g0, 299, 64, 64, 0, 1);
    add(g_w1,    Wt_g1, 64, 64, 64, 0, 1);
    add(g_w2,    Wt_g2, 64, 6, 32, 0, 1);
    add(w0,      Wt_w0, 299, 256, 256, 0, EXPERTS);
    add(w1,      Wt_w1, 288, 256, 256, 0, EXPERTS);
    add(w2,      Wt_w2, 288, 267, 320, 0, EXPERTS);
    tab.total = cum;

    const dim3 blk(256);
    const int gy   = N_BATCH / 16;   // 256 row-blocks (16-row kernels)
    const int gy32 = N_BATCH / 32;   // 128 row-blocks (32-row kernels)

    // 0) prep: cvt (512 blocks) + weight repack
    prep_kernel<<<dim3(512 + cum), blk, 0, stream>>>(x, c, enc_bmu, enc_blv,
        Axc, Axh1, Axh2, Azc, biasCat, tab);

    // 1) h1 = elu([x|c]@W+b) -> Axh1[:,267:523]   grid (4,256)=1024 blocks
    gemm16<17, 1><<<dim3(4, gy), blk, 0, stream>>>(Axc, Wt_e1, enc_b1,
        nullptr, 256, 256, nullptr, 0, Axh1 + FRAME, 544, 1);
    // 2) h2 = elu([x|h1]@W+b) -> Axh2[:,267:523]
    gemm16<17, 1><<<dim3(4, gy), blk, 0, stream>>>(Axh1, Wt_e2, enc_b2,
        nullptr, 256, 256, nullptr, 0, Axh2 + FRAME, 544, 1);
    // 3) mu|lv + z + gate chain + softmax (fused; 256 blocks)
    mid_kernel<<<dim3(gy), blk, 0, stream>>>(Axh2, Wt_ml, biasCat, eps,
        out_mu, out_lv, Azc, Azd1, Azd2, Wt_g0, Wt_g1, Wt_g2,
        g_b0, g_b1, g_b2, co);
    // 4) dh1 = elu(moe([z|c], w0, b0)) -> Azd1[:,32:288]   grid (4,128)=512
    gemm32<10, EXPERTS><<<dim3(4, gy32), blk, 0, stream>>>(Azc, Wt_w0, b0,
        co, 256, 256, nullptr, 0, Azd1 + LATENT, 288, 1);
    // 5) dh2 = elu(moe([z|dh1], w1, b1)) -> Azd2[:,32:288]
    gemm32<9, EXPERTS><<<dim3(4, gy32), blk, 0, stream>>>(Azd1, Wt_w1, b1,
        co, 256, 256, nullptr, 0, Azd2 + LATENT, 288, 1);
    // 6) out = moe([z|dh2], w2, b2) -> d_out (f32)   grid (5,128)=640
    gemm32<9, EXPERTS><<<dim3(5, gy32), blk, 0, stream>>>(Azd2, Wt_w2, b2,
        co, FRAME, 320, out_layer, FRAME, nullptr, 0, 0);
}

// Round 2
// 187.498 us; speedup vs baseline: 1.0781x; 1.0168x over previous
//
#include <hip/hip_runtime.h>
#include <hip/hip_bf16.h>
#include <math.h>

// Problem constants (PoseMixtureVAE)
#define N_BATCH 4096
#define FRAME   267
#define LATENT  32
#define HIDDEN  256
#define GATE_H  64
#define EXPERTS 6
// Kpads: [x|c]=534->544 (17 ksteps), [x|h]=523->544 (17), [z|c]=299->320 (10),
//        [z|h]=288 (9 exactly), gate hidden 64 (2)

typedef __hip_bfloat16 bf16;
typedef __bf16  bf16x8 __attribute__((ext_vector_type(8)));
typedef float   f32x4  __attribute__((ext_vector_type(4)));

__device__ __forceinline__ float eluf(float v) { return (v > 0.f) ? v : (expf(v) - 1.f); }

#define MFMA(a, b, p) __builtin_amdgcn_mfma_f32_16x16x32_bf16((a), (b), (p), 0, 0, 0)

struct WEnt { const float* src; bf16* dst; int K, M, Mtot, mOff, Ksteps, Mtiles, cum; };
struct WTab { WEnt e[10]; int total; };

// ---------------------------------------------------------------------------
// prep: weight repack (one 32x32 tile unit per block) + biasCat.
// Input conversion is gone — the fused kernel reads x/c/eps directly.
// ---------------------------------------------------------------------------
__global__ __launch_bounds__(256) void prep_kernel(
    const float* __restrict__ bmu, const float* __restrict__ blv,
    float* __restrict__ biasCat, WTab tab)
{
    const int tid = threadIdx.x, bid = blockIdx.x;
    if (bid == 0 && tid < 64)
        biasCat[tid] = (tid < 32) ? bmu[tid] : blv[tid - 32];

    __shared__ float tbuf[32][33];
    int i = 0;
    while (i < 9 && bid >= tab.e[i + 1].cum) ++i;
    const WEnt en = tab.e[i];
    const int t = bid - en.cum;
    const int perE = en.Ksteps * en.Mtiles;
    const int e = t / perE;
    const int rr = t - e * perE;
    const int mt = rr / en.Ksteps;
    const int ks = rr - mt * en.Ksteps;
    const int tx = tid & 31, ty = tid >> 5;
    const float* src = en.src + (size_t)e * en.K * en.M;
    #pragma unroll
    for (int i0 = 0; i0 < 32; i0 += 8) {
        const int k = ks * 32 + i0 + ty, m = mt * 32 + tx;
        tbuf[i0 + ty][tx] = (k < en.K && m < en.M) ? src[(size_t)k * en.M + m] : 0.f;
    }
    __syncthreads();
    bf16* dst = en.dst + ((size_t)(e * en.Ksteps + ks) * en.Mtot + en.mOff + mt * 32) * 32;
    #pragma unroll
    for (int i0 = 0; i0 < 32; i0 += 8)
        dst[(size_t)(i0 + ty) * 32 + tx] = __float2bfloat16(tbuf[tx][i0 + ty]);
}

// ---------------------------------------------------------------------------
// fused: the ENTIRE network for 16 rows per block. 256 blocks = 1/CU.
// 512 threads = 8 waves (2/SIMD). Phases separated by __syncthreads().
// bufA/bufB ping-pong (stride 552 bf16 = 1104B; row-delta = 20 banks -> the
// 64-lane b128 read is 2-way bank-aliased = free).
// A-fragments hoisted to registers per phase (ks-indexed, fully unrolled).
// Weight set (3.65MB bf16 repacked) is L2-resident per XCD.
// ---------------------------------------------------------------------------
__global__ __launch_bounds__(512, 2) void fused_kernel(
    const float* __restrict__ x, const float* __restrict__ c,
    const float* __restrict__ eps,
    const bf16* __restrict__ We1, const float* __restrict__ eb1,
    const bf16* __restrict__ We2, const float* __restrict__ eb2,
    const bf16* __restrict__ Wml, const float* __restrict__ biasCat,
    const bf16* __restrict__ Wg0, const float* __restrict__ gb0,
    const bf16* __restrict__ Wg1, const float* __restrict__ gb1,
    const bf16* __restrict__ Wg2, const float* __restrict__ gb2,
    const bf16* __restrict__ W0, const float* __restrict__ b0,
    const bf16* __restrict__ W1, const float* __restrict__ b1,
    const bf16* __restrict__ W2, const float* __restrict__ b2,
    float* __restrict__ out_layer, float* __restrict__ out_mu,
    float* __restrict__ out_lv)
{
    __shared__ bf16  bufA[16 * 552];
    __shared__ bf16  bufB[16 * 552];
    __shared__ float sML[16 * 64];
    __shared__ bf16  sG1[16 * 72];
    __shared__ bf16  sG2[16 * 72];
    __shared__ float sLg[16 * 16];
    __shared__ float sCo[EXPERTS * 16];

    const int tid  = threadIdx.x;
    const int w    = tid >> 6, lane = tid & 63, ml = lane & 15, quad = lane >> 4;
    const int row0 = blockIdx.x * 16;
    const int r32  = tid >> 5, l32 = tid & 31;   // 16 rows x 32 threads

    // ---- Ph0: bufA = [x|c] bf16 (Kpad 544, zero 534..543) ----
    {
        const float* xr = x + (size_t)(row0 + r32) * FRAME;
        const float* cr = c + (size_t)(row0 + r32) * FRAME;
        #pragma unroll
        for (int j = 0; j < 17; ++j) {
            const int col = l32 + j * 32;
            float v = 0.f;
            if (col < FRAME)          v = xr[col];
            else if (col < 2 * FRAME) v = cr[col - FRAME];
            bufA[r32 * 552 + col] = __float2bfloat16(v);
        }
    }
    __syncthreads();

    // ---- Ph1: h1 = elu([x|c] @ We1 + eb1), M=256; bufB = [x|h1] ----
    {
        bf16x8 av[17];
        #pragma unroll
        for (int ks = 0; ks < 17; ++ks)
            av[ks] = *(const bf16x8*)(bufA + ml * 552 + ks * 32 + quad * 8);
        const int col0 = 32 * w + ml;
        f32x4 p0 = (f32x4){0,0,0,0}, p1 = (f32x4){0,0,0,0};
        const bf16* wp = We1 + (size_t)col0 * 32 + quad * 8;
        #pragma unroll
        for (int ks = 0; ks < 17; ++ks) {
            p0 = MFMA(av[ks], *(const bf16x8*)(wp + (size_t)ks * 256 * 32), p0);
            p1 = MFMA(av[ks], *(const bf16x8*)(wp + (size_t)ks * 256 * 32 + 16 * 32), p1);
        }
        const float bv0 = eb1[col0], bv1 = eb1[col0 + 16];
        #pragma unroll
        for (int rg = 0; rg < 4; ++rg) {
            bufB[(quad * 4 + rg) * 552 + 267 + col0]      = __float2bfloat16(eluf(p0[rg] + bv0));
            bufB[(quad * 4 + rg) * 552 + 267 + col0 + 16] = __float2bfloat16(eluf(p1[rg] + bv1));
        }
        // copy x -> bufB[0..266]; zero bufB[523..543]
        #pragma unroll
        for (int j = 0; j < 9; ++j) {
            const int cc = l32 + j * 32;              // 0..287
            if (cc < 267) bufB[r32 * 552 + cc] = bufA[r32 * 552 + cc];
            else          bufB[r32 * 552 + (cc - 267 + 523)] = __float2bfloat16(0.f);
        }
    }
    __syncthreads();

    // ---- Ph2: h2 = elu([x|h1] @ We2 + eb2) -> bufB in-place = [x|h2] ----
    {
        bf16x8 av[17];
        #pragma unroll
        for (int ks = 0; ks < 17; ++ks)
            av[ks] = *(const bf16x8*)(bufB + ml * 552 + ks * 32 + quad * 8);
        const int col0 = 32 * w + ml;
        f32x4 p0 = (f32x4){0,0,0,0}, p1 = (f32x4){0,0,0,0};
        const bf16* wp = We2 + (size_t)col0 * 32 + quad * 8;
        #pragma unroll
        for (int ks = 0; ks < 17; ++ks) {
            p0 = MFMA(av[ks], *(const bf16x8*)(wp + (size_t)ks * 256 * 32), p0);
            p1 = MFMA(av[ks], *(const bf16x8*)(wp + (size_t)ks * 256 * 32 + 16 * 32), p1);
        }
        __syncthreads();   // all reads of bufB complete before overwrite
        const float bv0 = eb2[col0], bv1 = eb2[col0 + 16];
        #pragma unroll
        for (int rg = 0; rg < 4; ++rg) {
            bufB[(quad * 4 + rg) * 552 + 267 + col0]      = __float2bfloat16(eluf(p0[rg] + bv0));
            bufB[(quad * 4 + rg) * 552 + 267 + col0 + 16] = __float2bfloat16(eluf(p1[rg] + bv1));
        }
    }
    __syncthreads();

    // ---- Ph3: mu|lv = [x|h2] @ Wml + biasCat (M=64, waves 0..3) ----
    if (w < 4) {
        const int col = 16 * w + ml;
        f32x4 p = (f32x4){0,0,0,0};
        const bf16* wp = Wml + (size_t)col * 32 + quad * 8;
        #pragma unroll
        for (int ks = 0; ks < 17; ++ks) {
            const bf16x8 av = *(const bf16x8*)(bufB + ml * 552 + ks * 32 + quad * 8);
            p = MFMA(av, *(const bf16x8*)(wp + (size_t)ks * 64 * 32), p);
        }
        const float bv = biasCat[col];
        #pragma unroll
        for (int rg = 0; rg < 4; ++rg)
            sML[(quad * 4 + rg) * 64 + col] = p[rg] + bv;
    }
    __syncthreads();

    // ---- Ph3b: z = mu + eps*exp(0.5lv); bufB = [z|c] (Kpad 320); bufA[0..31]=z
    {
        const float m  = sML[r32 * 64 + l32];
        const float lv = sML[r32 * 64 + 32 + l32];
        const int gi = (row0 + r32) * LATENT + l32;
        out_mu[gi] = m; out_lv[gi] = lv;
        const bf16 zb = __float2bfloat16(m + eps[gi] * expf(0.5f * lv));
        bufA[r32 * 552 + l32] = zb;       // prefix of [z|dh1]
        bufB[r32 * 552 + l32] = zb;       // prefix of [z|c]
        #pragma unroll
        for (int j = 0; j < 9; ++j) {
            const int col = 32 + l32 + j * 32;        // 32..319
            bf16 v = __float2bfloat16(0.f);
            if (col < 299) v = bufA[r32 * 552 + 267 + (col - 32)];   // c
            bufB[r32 * 552 + col] = v;
        }
    }
    __syncthreads();

    // ---- Ph4a: g1 = elu([z|c] @ Wg0 + gb0), M=64 ----
    if (w < 4) {
        const int col = 16 * w + ml;
        f32x4 p = (f32x4){0,0,0,0};
        const bf16* wp = Wg0 + (size_t)col * 32 + quad * 8;
        #pragma unroll
        for (int ks = 0; ks < 10; ++ks)
            p = MFMA(*(const bf16x8*)(bufB + ml * 552 + ks * 32 + quad * 8),
                     *(const bf16x8*)(wp + (size_t)ks * 64 * 32), p);
        const float bv = gb0[col];
        #pragma unroll
        for (int rg = 0; rg < 4; ++rg)
            sG1[(quad * 4 + rg) * 72 + col] = __float2bfloat16(eluf(p[rg] + bv));
    }
    __syncthreads();

    // ---- Ph4b: g2 = elu(g1 @ Wg1 + gb1), M=64 ----
    if (w < 4) {
        const int col = 16 * w + ml;
        f32x4 p = (f32x4){0,0,0,0};
        const bf16* wp = Wg1 + (size_t)col * 32 + quad * 8;
        #pragma unroll
        for (int ks = 0; ks < 2; ++ks)
            p = MFMA(*(const bf16x8*)(sG1 + ml * 72 + ks * 32 + quad * 8),
                     *(const bf16x8*)(wp + (size_t)ks * 64 * 32), p);
        const float bv = gb1[col];
        #pragma unroll
        for (int rg = 0; rg < 4; ++rg)
            sG2[(quad * 4 + rg) * 72 + col] = __float2bfloat16(eluf(p[rg] + bv));
    }
    __syncthreads();

    // ---- Ph4c: logits = g2 @ Wg2 + gb2 (M=6, Mtot 32), wave 0 ----
    if (w == 0) {
        f32x4 p = (f32x4){0,0,0,0};
        const bf16* wp = Wg2 + (size_t)ml * 32 + quad * 8;
        #pragma unroll
        for (int ks = 0; ks < 2; ++ks)
            p = MFMA(*(const bf16x8*)(sG2 + ml * 72 + ks * 32 + quad * 8),
                     *(const bf16x8*)(wp + (size_t)ks * 32 * 32), p);
        const float bv = (ml < EXPERTS) ? gb2[ml] : 0.f;
        #pragma unroll
        for (int rg = 0; rg < 4; ++rg)
            sLg[(quad * 4 + rg) * 16 + ml] = p[rg] + bv;
    }
    __syncthreads();

    // ---- Ph4d: softmax -> sCo[e*16 + r] ----
    if (tid < 16) {
        float v[EXPERTS];
        float m = -1e30f;
        #pragma unroll
        for (int i = 0; i < EXPERTS; ++i) { v[i] = sLg[tid * 16 + i]; m = fmaxf(m, v[i]); }
        float s = 0.f;
        #pragma unroll
        for (int i = 0; i < EXPERTS; ++i) { v[i] = expf(v[i] - m); s += v[i]; }
        const float inv = 1.f / s;
        #pragma unroll
        for (int i = 0; i < EXPERTS; ++i) sCo[i * 16 + tid] = v[i] * inv;
    }
    __syncthreads();

    // ---- Ph5: dh1 = elu(moe([z|c], W0, b0)), M=256 -> bufA = [z|dh1] ----
    {
        bf16x8 av[10];
        #pragma unroll
        for (int ks = 0; ks < 10; ++ks)
            av[ks] = *(const bf16x8*)(bufB + ml * 552 + ks * 32 + quad * 8);
        const int col0 = 32 * w + ml;
        f32x4 acc0 = (f32x4){0,0,0,0}, acc1 = (f32x4){0,0,0,0};
        for (int e = 0; e < EXPERTS; ++e) {
            f32x4 p0 = (f32x4){0,0,0,0}, p1 = (f32x4){0,0,0,0};
            const bf16* wp = W0 + ((size_t)e * 10 * 256 + col0) * 32 + quad * 8;
            #pragma unroll
            for (int ks = 0; ks < 10; ++ks) {
                p0 = MFMA(av[ks], *(const bf16x8*)(wp + (size_t)ks * 256 * 32), p0);
                p1 = MFMA(av[ks], *(const bf16x8*)(wp + (size_t)ks * 256 * 32 + 16 * 32), p1);
            }
            const float bv0 = b0[e * 256 + col0], bv1 = b0[e * 256 + col0 + 16];
            #pragma unroll
            for (int rg = 0; rg < 4; ++rg) {
                const float cf = sCo[e * 16 + quad * 4 + rg];
                acc0[rg] += cf * (p0[rg] + bv0);
                acc1[rg] += cf * (p1[rg] + bv1);
            }
        }
        #pragma unroll
        for (int rg = 0; rg < 4; ++rg) {
            bufA[(quad * 4 + rg) * 552 + 32 + col0]      = __float2bfloat16(eluf(acc0[rg]));
            bufA[(quad * 4 + rg) * 552 + 32 + col0 + 16] = __float2bfloat16(eluf(acc1[rg]));
        }
    }
    __syncthreads();

    // ---- Ph6: dh2 = elu(moe([z|dh1], W1, b1)), M=256 -> bufB = [z|dh2] ----
    {
        bf16x8 av[9];
        #pragma unroll
        for (int ks = 0; ks < 9; ++ks)
            av[ks] = *(const bf16x8*)(bufA + ml * 552 + ks * 32 + quad * 8);
        const int col0 = 32 * w + ml;
        f32x4 acc0 = (f32x4){0,0,0,0}, acc1 = (f32x4){0,0,0,0};
        for (int e = 0; e < EXPERTS; ++e) {
            f32x4 p0 = (f32x4){0,0,0,0}, p1 = (f32x4){0,0,0,0};
            const bf16* wp = W1 + ((size_t)e * 9 * 256 + col0) * 32 + quad * 8;
            #pragma unroll
            for (int ks = 0; ks < 9; ++ks) {
                p0 = MFMA(av[ks], *(const bf16x8*)(wp + (size_t)ks * 256 * 32), p0);
                p1 = MFMA(av[ks], *(const bf16x8*)(wp + (size_t)ks * 256 * 32 + 16 * 32), p1);
            }
            const float bv0 = b1[e * 256 + col0], bv1 = b1[e * 256 + col0 + 16];
            #pragma unroll
            for (int rg = 0; rg < 4; ++rg) {
                const float cf = sCo[e * 16 + quad * 4 + rg];
                acc0[rg] += cf * (p0[rg] + bv0);
                acc1[rg] += cf * (p1[rg] + bv1);
            }
        }
        __syncthreads();   // Ph5 readers of bufB are done (barrier above), but
                           // ensure all waves finished reading bufA this phase
                           // before... (writes go to bufB — safe) — kept for clarity
        #pragma unroll
        for (int rg = 0; rg < 4; ++rg) {
            bufB[(quad * 4 + rg) * 552 + 32 + col0]      = __float2bfloat16(eluf(acc0[rg]));
            bufB[(quad * 4 + rg) * 552 + 32 + col0 + 16] = __float2bfloat16(eluf(acc1[rg]));
        }
    }
    __syncthreads();

    // ---- Ph7: out = moe([z|dh2], W2, b2), M=267 (tiles 0..17) -> global ----
    {
        bf16x8 av[9];
        #pragma unroll
        for (int ks = 0; ks < 9; ++ks)
            av[ks] = *(const bf16x8*)(bufB + ml * 552 + ks * 32 + quad * 8);
        for (int t = w; t < 18; t += 8) {
            const int col = 16 * t + ml;
            f32x4 acc = (f32x4){0,0,0,0};
            for (int e = 0; e < EXPERTS; ++e) {
                f32x4 p = (f32x4){0,0,0,0};
                const bf16* wp = W2 + ((size_t)e * 9 * 320 + col) * 32 + quad * 8;
                #pragma unroll
                for (int ks = 0; ks < 9; ++ks)
                    p = MFMA(av[ks], *(const bf16x8*)(wp + (size_t)ks * 320 * 32), p);
                const float bv = (col < FRAME) ? b2[e * FRAME + col] : 0.f;
                #pragma unroll
                for (int rg = 0; rg < 4; ++rg)
                    acc[rg] += sCo[e * 16 + quad * 4 + rg] * (p[rg] + bv);
            }
            if (col < FRAME) {
                #pragma unroll
                for (int rg = 0; rg < 4; ++rg)
                    out_layer[(size_t)(row0 + quad * 4 + rg) * FRAME + col] = acc[rg];
            }
        }
    }
}

// ---------------------------------------------------------------------------
extern "C" void kernel_launch(void* const* d_in, const int* in_sizes, int n_in,
                              void* d_out, int out_size, void* d_ws, size_t ws_size,
                              hipStream_t stream) {
    const float* x       = (const float*)d_in[0];
    const float* c       = (const float*)d_in[1];
    const float* eps     = (const float*)d_in[2];
    const float* enc_w1  = (const float*)d_in[3];
    const float* enc_b1  = (const float*)d_in[4];
    const float* enc_w2  = (const float*)d_in[5];
    const float* enc_b2  = (const float*)d_in[6];
    const float* enc_wmu = (const float*)d_in[7];
    const float* enc_bmu = (const float*)d_in[8];
    const float* enc_wlv = (const float*)d_in[9];
    const float* enc_blv = (const float*)d_in[10];
    const float* g_w0    = (const float*)d_in[11];
    const float* g_b0    = (const float*)d_in[12];
    const float* g_w1    = (const float*)d_in[13];
    const float* g_b1    = (const float*)d_in[14];
    const float* g_w2    = (const float*)d_in[15];
    const float* g_b2    = (const float*)d_in[16];
    const float* w0      = (const float*)d_in[17];
    const float* b0      = (const float*)d_in[18];
    const float* w1      = (const float*)d_in[19];
    const float* b1      = (const float*)d_in[20];
    const float* w2      = (const float*)d_in[21];
    const float* b2      = (const float*)d_in[22];

    // output (f32): [layer (4096x267) | mu (4096x32) | logvar (4096x32)]
    float* out_layer = (float*)d_out;
    float* out_mu    = out_layer + (size_t)N_BATCH * FRAME;
    float* out_lv    = out_mu    + (size_t)N_BATCH * LATENT;

    // ---- workspace layout (16B-aligned): biasCat + repacked weights only ----
    char* p = (char*)d_ws;
    float* biasCat = (float*)p;  p += 64 * 4;
    bf16* Wt_e1 = (bf16*)p;      p += (size_t)17 * 256 * 32 * 2;
    bf16* Wt_e2 = (bf16*)p;      p += (size_t)17 * 256 * 32 * 2;
    bf16* Wt_ml = (bf16*)p;      p += (size_t)17 * 64 * 32 * 2;
    bf16* Wt_g0 = (bf16*)p;      p += (size_t)10 * 64 * 32 * 2;
    bf16* Wt_g1 = (bf16*)p;      p += (size_t)2 * 64 * 32 * 2;
    bf16* Wt_g2 = (bf16*)p;      p += (size_t)2 * 32 * 32 * 2;
    bf16* Wt_w0 = (bf16*)p;      p += (size_t)EXPERTS * 10 * 256 * 32 * 2;
    bf16* Wt_w1 = (bf16*)p;      p += (size_t)EXPERTS * 9 * 256 * 32 * 2;
    bf16* Wt_w2 = (bf16*)p;      p += (size_t)EXPERTS * 9 * 320 * 32 * 2;

    WTab tab;
    int cum = 0, n = 0;
    auto add = [&](const float* src, bf16* dst, int K, int M, int Mtot, int mOff, int E) {
        int Ksteps;
        if (K == 534 || K == 523) Ksteps = 17;
        else if (K == 299) Ksteps = 10;
        else if (K == 288) Ksteps = 9;
        else Ksteps = 2;   // K=64
        const int Mtiles = (M + 31) / 32;
        tab.e[n] = {src, dst, K, M, Mtot, mOff, Ksteps, Mtiles, cum};
        cum += E * Ksteps * Mtiles;
        ++n;
    };
    add(enc_w1,  Wt_e1, 534, 256, 256, 0, 1);
    add(enc_w2,  Wt_e2, 523, 256, 256, 0, 1);
    add(enc_wmu, Wt_ml, 523, 32, 64, 0, 1);
    add(enc_wlv, Wt_ml, 523, 32, 64, 32, 1);
    add(g_w0,    Wt_g0, 299, 64, 64, 0, 1);
    add(g_w1,    Wt_g1, 64, 64, 64, 0, 1);
    add(g_w2,    Wt_g2, 64, 6, 32, 0, 1);
    add(w0,      Wt_w0, 299, 256, 256, 0, EXPERTS);
    add(w1,      Wt_w1, 288, 256, 256, 0, EXPERTS);
    add(w2,      Wt_w2, 288, 267, 320, 0, EXPERTS);
    tab.total = cum;

    // 0) prep: weight repack (cum blocks) + biasCat
    prep_kernel<<<dim3(cum), dim3(256), 0, stream>>>(enc_bmu, enc_blv, biasCat, tab);

    // 1) fully fused network: 256 blocks x 512 threads (1 block/CU, 8 waves)
    fused_kernel<<<dim3(N_BATCH / 16), dim3(512), 0, stream>>>(
        x, c, eps,
        Wt_e1, enc_b1, Wt_e2, enc_b2, Wt_ml, biasCat,
        Wt_g0, g_b0, Wt_g1, g_b1, Wt_g2, g_b2,
        Wt_w0, b0, Wt_w1, b1, Wt_w2, b2,
        out_layer, out_mu, out_lv);
}

// Round 4
// 171.808 us; speedup vs baseline: 1.1765x; 1.0913x over previous
//
#include <hip/hip_runtime.h>
#include <hip/hip_bf16.h>
#include <math.h>

// Problem constants (PoseMixtureVAE)
#define N_BATCH 4096
#define FRAME   267
#define LATENT  32
#define HIDDEN  256
#define GATE_H  64
#define EXPERTS 6
// Kpads: [x|c]=534->544 (17 ksteps), [x|h]=523->544 (17), [z|c]=299->320 (10),
//        [z|h]=288 (9 exactly), gate hidden 64 (2)

typedef __hip_bfloat16 bf16;
typedef __bf16  bf16x8 __attribute__((ext_vector_type(8)));
typedef float   f32x4  __attribute__((ext_vector_type(4)));

__device__ __forceinline__ float eluf(float v) { return (v > 0.f) ? v : (expf(v) - 1.f); }

#define MFMA(a, b, p) __builtin_amdgcn_mfma_f32_16x16x32_bf16((a), (b), (p), 0, 0, 0)

struct WEnt { const float* src; bf16* dst; int K, M, Mtot, mOff, Ksteps, Mtiles, cum; };
struct WTab { WEnt e[10]; int total; };

// ---------------------------------------------------------------------------
// prep: weight repack (one 32x32 tile unit per block) + biasCat.
// ---------------------------------------------------------------------------
__global__ __launch_bounds__(256) void prep_kernel(
    const float* __restrict__ bmu, const float* __restrict__ blv,
    float* __restrict__ biasCat, WTab tab)
{
    const int tid = threadIdx.x, bid = blockIdx.x;
    if (bid == 0 && tid < 64)
        biasCat[tid] = (tid < 32) ? bmu[tid] : blv[tid - 32];

    __shared__ float tbuf[32][33];
    int i = 0;
    while (i < 9 && bid >= tab.e[i + 1].cum) ++i;
    const WEnt en = tab.e[i];
    const int t = bid - en.cum;
    const int perE = en.Ksteps * en.Mtiles;
    const int e = t / perE;
    const int rr = t - e * perE;
    const int mt = rr / en.Ksteps;
    const int ks = rr - mt * en.Ksteps;
    const int tx = tid & 31, ty = tid >> 5;
    const float* src = en.src + (size_t)e * en.K * en.M;
    #pragma unroll
    for (int i0 = 0; i0 < 32; i0 += 8) {
        const int k = ks * 32 + i0 + ty, m = mt * 32 + tx;
        tbuf[i0 + ty][tx] = (k < en.K && m < en.M) ? src[(size_t)k * en.M + m] : 0.f;
    }
    __syncthreads();
    bf16* dst = en.dst + ((size_t)(e * en.Ksteps + ks) * en.Mtot + en.mOff + mt * 32) * 32;
    #pragma unroll
    for (int i0 = 0; i0 < 32; i0 += 8)
        dst[(size_t)(i0 + ty) * 32 + tx] = __float2bfloat16(tbuf[tx][i0 + ty]);
}

// ---------------------------------------------------------------------------
// fused: the ENTIRE network for 16 rows per block. 256 blocks = 1/CU.
// 1024 threads = 16 waves (4/SIMD resident) for latency hiding on the L2
// B-stream. M=256 phases: wave w owns col-tile w (RF=1). Gate chain
// (waves 0-3) is interleaved with Ph5's expert partials (blend deferred
// until sCo ready). __launch_bounds__(1024,2): 256-VGPR cap — residency is
// block-granular (1 block/CU = 4 waves/SIMD either way), so take the
// register headroom and avoid Ph5 spills.
// ---------------------------------------------------------------------------
__global__ __launch_bounds__(1024, 2) void fused_kernel(
    const float* __restrict__ x, const float* __restrict__ c,
    const float* __restrict__ eps,
    const bf16* __restrict__ We1, const float* __restrict__ eb1,
    const bf16* __restrict__ We2, const float* __restrict__ eb2,
    const bf16* __restrict__ Wml, const float* __restrict__ biasCat,
    const bf16* __restrict__ Wg0, const float* __restrict__ gb0,
    const bf16* __restrict__ Wg1, const float* __restrict__ gb1,
    const bf16* __restrict__ Wg2, const float* __restrict__ gb2,
    const bf16* __restrict__ W0, const float* __restrict__ b0,
    const bf16* __restrict__ W1, const float* __restrict__ b1,
    const bf16* __restrict__ W2, const float* __restrict__ b2,
    float* __restrict__ out_layer, float* __restrict__ out_mu,
    float* __restrict__ out_lv)
{
    __shared__ bf16  bufA[16 * 552];
    __shared__ bf16  bufB[16 * 552];
    __shared__ float sML[16 * 64];
    __shared__ bf16  sG1[16 * 72];
    __shared__ bf16  sG2[16 * 72];
    __shared__ float sLg[16 * 16];
    __shared__ float sCo[EXPERTS * 16];

    const int tid  = threadIdx.x;
    const int w    = tid >> 6, lane = tid & 63, ml = lane & 15, quad = lane >> 4;
    const int row0 = blockIdx.x * 16;

    // ---- Ph0: bufA = [x|c] bf16 (Kpad 544, zero 534..543). row = w. ----
    {
        const float* xr = x + (size_t)(row0 + w) * FRAME;
        const float* cr = c + (size_t)(row0 + w) * FRAME;
        #pragma unroll
        for (int j = 0; j < 9; ++j) {
            const int col = lane + j * 64;
            if (col < 544) {
                float v = 0.f;
                if (col < FRAME)          v = xr[col];
                else if (col < 2 * FRAME) v = cr[col - FRAME];
                bufA[w * 552 + col] = __float2bfloat16(v);
            }
        }
    }
    __syncthreads();

    // ---- Ph1: h1 = elu([x|c] @ We1 + eb1), M=256 (16 tiles); bufB=[x|h1] ----
    {
        const int col = 16 * w + ml;
        f32x4 p = (f32x4){0,0,0,0};
        const bf16* wp = We1 + (size_t)col * 32 + quad * 8;
        #pragma unroll
        for (int ks = 0; ks < 17; ++ks) {
            const bf16x8 a = *(const bf16x8*)(bufA + ml * 552 + ks * 32 + quad * 8);
            p = MFMA(a, *(const bf16x8*)(wp + (size_t)ks * 256 * 32), p);
        }
        const float bv = eb1[col];
        #pragma unroll
        for (int rg = 0; rg < 4; ++rg)
            bufB[(quad * 4 + rg) * 552 + 267 + col] = __float2bfloat16(eluf(p[rg] + bv));
        // copy x -> bufB[0..266] (row w); zero pad 523..543
        #pragma unroll
        for (int j = 0; j < 5; ++j) {
            const int cc = lane + j * 64;
            if (cc < 267) bufB[w * 552 + cc] = bufA[w * 552 + cc];
        }
        if (lane < 21) bufB[w * 552 + 523 + lane] = __float2bfloat16(0.f);
    }
    __syncthreads();

    // ---- Ph2: h2 = elu([x|h1] @ We2 + eb2) -> bufB in-place = [x|h2] ----
    {
        const int col = 16 * w + ml;
        f32x4 p = (f32x4){0,0,0,0};
        const bf16* wp = We2 + (size_t)col * 32 + quad * 8;
        #pragma unroll
        for (int ks = 0; ks < 17; ++ks) {
            const bf16x8 a = *(const bf16x8*)(bufB + ml * 552 + ks * 32 + quad * 8);
            p = MFMA(a, *(const bf16x8*)(wp + (size_t)ks * 256 * 32), p);
        }
        __syncthreads();   // all reads of bufB done before overwrite
        const float bv = eb2[col];
        #pragma unroll
        for (int rg = 0; rg < 4; ++rg)
            bufB[(quad * 4 + rg) * 552 + 267 + col] = __float2bfloat16(eluf(p[rg] + bv));
    }
    __syncthreads();

    // ---- Ph3: mu|lv = [x|h2] @ Wml + biasCat (M=64, waves 0..3) ----
    if (w < 4) {
        const int col = 16 * w + ml;
        f32x4 p = (f32x4){0,0,0,0};
        const bf16* wp = Wml + (size_t)col * 32 + quad * 8;
        #pragma unroll
        for (int ks = 0; ks < 17; ++ks) {
            const bf16x8 a = *(const bf16x8*)(bufB + ml * 552 + ks * 32 + quad * 8);
            p = MFMA(a, *(const bf16x8*)(wp + (size_t)ks * 64 * 32), p);
        }
        const float bv = biasCat[col];
        #pragma unroll
        for (int rg = 0; rg < 4; ++rg)
            sML[(quad * 4 + rg) * 64 + col] = p[rg] + bv;
    }
    __syncthreads();

    // ---- Ph3b: z; bufB = [z|c] (Kpad 320); bufA[0..31] = z ----
    if (tid < 512) {
        const int r = tid >> 5, l = tid & 31;
        const float m  = sML[r * 64 + l];
        const float lv = sML[r * 64 + 32 + l];
        const int gi = (row0 + r) * LATENT + l;
        out_mu[gi] = m; out_lv[gi] = lv;
        const bf16 zb = __float2bfloat16(m + eps[gi] * expf(0.5f * lv));
        bufA[r * 552 + l] = zb;       // prefix of [z|dh1]
        bufB[r * 552 + l] = zb;       // prefix of [z|c]
        #pragma unroll
        for (int j = 0; j < 9; ++j) {
            const int col = 32 + l + j * 32;          // 32..319
            bf16 v = __float2bfloat16(0.f);
            if (col < 299) v = bufA[r * 552 + 267 + (col - 32)];   // c
            bufB[r * 552 + col] = v;
        }
    }
    __syncthreads();

    // ---- Ph5 + gate overlap: expert partials (all 16 waves) interleaved
    //      with gate chain (waves 0-3); blend after sCo ready -> bufA=[z|dh1]
    {
        const int col = 16 * w + ml;
        bf16x8 av[10];
        #pragma unroll
        for (int ks = 0; ks < 10; ++ks)
            av[ks] = *(const bf16x8*)(bufB + ml * 552 + ks * 32 + quad * 8);

        auto moe_part = [&](int e, f32x4& p) {
            const bf16* wp = W0 + ((size_t)e * 10 * 256 + col) * 32 + quad * 8;
            #pragma unroll
            for (int ks = 0; ks < 10; ++ks)
                p = MFMA(av[ks], *(const bf16x8*)(wp + (size_t)ks * 256 * 32), p);
        };

        f32x4 pe0 = (f32x4){0,0,0,0}, pe1 = (f32x4){0,0,0,0}, pe2 = (f32x4){0,0,0,0};
        f32x4 pe3 = (f32x4){0,0,0,0}, pe4 = (f32x4){0,0,0,0}, pe5 = (f32x4){0,0,0,0};

        // chunk 1: g1 (waves 0-3; A-fragment == av) + experts 0,1
        if (w < 4) {
            f32x4 p = (f32x4){0,0,0,0};
            const bf16* wp = Wg0 + (size_t)col * 32 + quad * 8;
            #pragma unroll
            for (int ks = 0; ks < 10; ++ks)
                p = MFMA(av[ks], *(const bf16x8*)(wp + (size_t)ks * 64 * 32), p);
            const float bv = gb0[col];
            #pragma unroll
            for (int rg = 0; rg < 4; ++rg)
                sG1[(quad * 4 + rg) * 72 + col] = __float2bfloat16(eluf(p[rg] + bv));
        }
        moe_part(0, pe0); moe_part(1, pe1);
        __syncthreads();

        // chunk 2: g2 + experts 2,3
        if (w < 4) {
            f32x4 p = (f32x4){0,0,0,0};
            const bf16* wp = Wg1 + (size_t)col * 32 + quad * 8;
            #pragma unroll
            for (int ks = 0; ks < 2; ++ks)
                p = MFMA(*(const bf16x8*)(sG1 + ml * 72 + ks * 32 + quad * 8),
                         *(const bf16x8*)(wp + (size_t)ks * 64 * 32), p);
            const float bv = gb1[col];
            #pragma unroll
            for (int rg = 0; rg < 4; ++rg)
                sG2[(quad * 4 + rg) * 72 + col] = __float2bfloat16(eluf(p[rg] + bv));
        }
        moe_part(2, pe2); moe_part(3, pe3);
        __syncthreads();

        // chunk 3: logits (wave 0) + expert 4
        if (w == 0) {
            f32x4 p = (f32x4){0,0,0,0};
            const bf16* wp = Wg2 + (size_t)ml * 32 + quad * 8;
            #pragma unroll
            for (int ks = 0; ks < 2; ++ks)
                p = MFMA(*(const bf16x8*)(sG2 + ml * 72 + ks * 32 + quad * 8),
                         *(const bf16x8*)(wp + (size_t)ks * 32 * 32), p);
            const float bv = (ml < EXPERTS) ? gb2[ml] : 0.f;
            #pragma unroll
            for (int rg = 0; rg < 4; ++rg)
                sLg[(quad * 4 + rg) * 16 + ml] = p[rg] + bv;
        }
        moe_part(4, pe4);
        __syncthreads();

        // chunk 4: softmax (lanes 0-15 of wave 0) + expert 5
        if (tid < 16) {
            float v[EXPERTS];
            float m = -1e30f;
            #pragma unroll
            for (int i = 0; i < EXPERTS; ++i) { v[i] = sLg[tid * 16 + i]; m = fmaxf(m, v[i]); }
            float s = 0.f;
            #pragma unroll
            for (int i = 0; i < EXPERTS; ++i) { v[i] = expf(v[i] - m); s += v[i]; }
            const float inv = 1.f / s;
            #pragma unroll
            for (int i = 0; i < EXPERTS; ++i) sCo[i * 16 + tid] = v[i] * inv;
        }
        moe_part(5, pe5);
        __syncthreads();

        // blend with coefficients + bias, write dh1
        f32x4 acc = (f32x4){0,0,0,0};
        auto blend = [&](const f32x4& p, int e) {
            const float bv = b0[e * 256 + col];
            #pragma unroll
            for (int rg = 0; rg < 4; ++rg)
                acc[rg] += sCo[e * 16 + quad * 4 + rg] * (p[rg] + bv);
        };
        blend(pe0, 0); blend(pe1, 1); blend(pe2, 2);
        blend(pe3, 3); blend(pe4, 4); blend(pe5, 5);
        #pragma unroll
        for (int rg = 0; rg < 4; ++rg)
            bufA[(quad * 4 + rg) * 552 + 32 + col] = __float2bfloat16(eluf(acc[rg]));
    }
    __syncthreads();

    // ---- Ph6: dh2 = elu(moe([z|dh1], W1, b1)), M=256 -> bufB = [z|dh2] ----
    {
        const int col = 16 * w + ml;
        bf16x8 av[9];
        #pragma unroll
        for (int ks = 0; ks < 9; ++ks)
            av[ks] = *(const bf16x8*)(bufA + ml * 552 + ks * 32 + quad * 8);
        f32x4 acc = (f32x4){0,0,0,0};
        #pragma unroll
        for (int e = 0; e < EXPERTS; ++e) {
            f32x4 p = (f32x4){0,0,0,0};
            const bf16* wp = W1 + ((size_t)e * 9 * 256 + col) * 32 + quad * 8;
            #pragma unroll
            for (int ks = 0; ks < 9; ++ks)
                p = MFMA(av[ks], *(const bf16x8*)(wp + (size_t)ks * 256 * 32), p);
            const float bv = b1[e * 256 + col];
            #pragma unroll
            for (int rg = 0; rg < 4; ++rg)
                acc[rg] += sCo[e * 16 + quad * 4 + rg] * (p[rg] + bv);
        }
        // writes go to bufB; last bufB reads were before the Ph5-end barrier
        #pragma unroll
        for (int rg = 0; rg < 4; ++rg)
            bufB[(quad * 4 + rg) * 552 + 32 + col] = __float2bfloat16(eluf(acc[rg]));
    }
    __syncthreads();

    // ---- Ph7: out = moe([z|dh2], W2, b2), M=267 (18 tiles) -> global ----
    {
        bf16x8 av[9];
        #pragma unroll
        for (int ks = 0; ks < 9; ++ks)
            av[ks] = *(const bf16x8*)(bufB + ml * 552 + ks * 32 + quad * 8);
        for (int t = w; t < 18; t += 16) {
            const int col = 16 * t + ml;
            f32x4 acc = (f32x4){0,0,0,0};
            #pragma unroll
            for (int e = 0; e < EXPERTS; ++e) {
                f32x4 p = (f32x4){0,0,0,0};
                const bf16* wp = W2 + ((size_t)e * 9 * 320 + col) * 32 + quad * 8;
                #pragma unroll
                for (int ks = 0; ks < 9; ++ks)
                    p = MFMA(av[ks], *(const bf16x8*)(wp + (size_t)ks * 320 * 32), p);
                const float bv = (col < FRAME) ? b2[e * FRAME + col] : 0.f;
                #pragma unroll
                for (int rg = 0; rg < 4; ++rg)
                    acc[rg] += sCo[e * 16 + quad * 4 + rg] * (p[rg] + bv);
            }
            if (col < FRAME) {
                #pragma unroll
                for (int rg = 0; rg < 4; ++rg)
                    out_layer[(size_t)(row0 + quad * 4 + rg) * FRAME + col] = acc[rg];
            }
        }
    }
}

// ---------------------------------------------------------------------------
extern "C" void kernel_launch(void* const* d_in, const int* in_sizes, int n_in,
                              void* d_out, int out_size, void* d_ws, size_t ws_size,
                              hipStream_t stream) {
    const float* x       = (const float*)d_in[0];
    const float* c       = (const float*)d_in[1];
    const float* eps     = (const float*)d_in[2];
    const float* enc_w1  = (const float*)d_in[3];
    const float* enc_b1  = (const float*)d_in[4];
    const float* enc_w2  = (const float*)d_in[5];
    const float* enc_b2  = (const float*)d_in[6];
    const float* enc_wmu = (const float*)d_in[7];
    const float* enc_bmu = (const float*)d_in[8];
    const float* enc_wlv = (const float*)d_in[9];
    const float* enc_blv = (const float*)d_in[10];
    const float* g_w0    = (const float*)d_in[11];
    const float* g_b0    = (const float*)d_in[12];
    const float* g_w1    = (const float*)d_in[13];
    const float* g_b1    = (const float*)d_in[14];
    const float* g_w2    = (const float*)d_in[15];
    const float* g_b2    = (const float*)d_in[16];
    const float* w0      = (const float*)d_in[17];
    const float* b0      = (const float*)d_in[18];
    const float* w1      = (const float*)d_in[19];
    const float* b1      = (const float*)d_in[20];
    const float* w2      = (const float*)d_in[21];
    const float* b2      = (const float*)d_in[22];

    // output (f32): [layer (4096x267) | mu (4096x32) | logvar (4096x32)]
    float* out_layer = (float*)d_out;
    float* out_mu    = out_layer + (size_t)N_BATCH * FRAME;
    float* out_lv    = out_mu    + (size_t)N_BATCH * LATENT;

    // ---- workspace layout (16B-aligned): biasCat + repacked weights only ----
    char* p = (char*)d_ws;
    float* biasCat = (float*)p;  p += 64 * 4;
    bf16* Wt_e1 = (bf16*)p;      p += (size_t)17 * 256 * 32 * 2;
    bf16* Wt_e2 = (bf16*)p;      p += (size_t)17 * 256 * 32 * 2;
    bf16* Wt_ml = (bf16*)p;      p += (size_t)17 * 64 * 32 * 2;
    bf16* Wt_g0 = (bf16*)p;      p += (size_t)10 * 64 * 32 * 2;
    bf16* Wt_g1 = (bf16*)p;      p += (size_t)2 * 64 * 32 * 2;
    bf16* Wt_g2 = (bf16*)p;      p += (size_t)2 * 32 * 32 * 2;
    bf16* Wt_w0 = (bf16*)p;      p += (size_t)EXPERTS * 10 * 256 * 32 * 2;
    bf16* Wt_w1 = (bf16*)p;      p += (size_t)EXPERTS * 9 * 256 * 32 * 2;
    bf16* Wt_w2 = (bf16*)p;      p += (size_t)EXPERTS * 9 * 320 * 32 * 2;

    WTab tab;
    int cum = 0, n = 0;
    auto add = [&](const float* src, bf16* dst, int K, int M, int Mtot, int mOff, int E) {
        int Ksteps;
        if (K == 534 || K == 523) Ksteps = 17;
        else if (K == 299) Ksteps = 10;
        else if (K == 288) Ksteps = 9;
        else Ksteps = 2;   // K=64
        const int Mtiles = (M + 31) / 32;
        tab.e[n] = {src, dst, K, M, Mtot, mOff, Ksteps, Mtiles, cum};
        cum += E * Ksteps * Mtiles;
        ++n;
    };
    add(enc_w1,  Wt_e1, 534, 256, 256, 0, 1);
    add(enc_w2,  Wt_e2, 523, 256, 256, 0, 1);
    add(enc_wmu, Wt_ml, 523, 32, 64, 0, 1);
    add(enc_wlv, Wt_ml, 523, 32, 64, 32, 1);
    add(g_w0,    Wt_g0, 299, 64, 64, 0, 1);
    add(g_w1,    Wt_g1, 64, 64, 64, 0, 1);
    add(g_w2,    Wt_g2, 64, 6, 32, 0, 1);
    add(w0,      Wt_w0, 299, 256, 256, 0, EXPERTS);
    add(w1,      Wt_w1, 288, 256, 256, 0, EXPERTS);
    add(w2,      Wt_w2, 288, 267, 320, 0, EXPERTS);
    tab.total = cum;

    // 0) prep: weight repack (cum blocks) + biasCat
    prep_kernel<<<dim3(cum), dim3(256), 0, stream>>>(enc_bmu, enc_blv, biasCat, tab);

    // 1) fully fused network: 256 blocks x 1024 threads (1 block/CU, 16 waves)
    fused_kernel<<<dim3(N_BATCH / 16), dim3(1024), 0, stream>>>(
        x, c, eps,
        Wt_e1, enc_b1, Wt_e2, enc_b2, Wt_ml, biasCat,
        Wt_g0, g_b0, Wt_g1, g_b1, Wt_g2, g_b2,
        Wt_w0, b0, Wt_w1, b1, Wt_w2, b2,
        out_layer, out_mu, out_lv);
}